// Round 16
// baseline (1895.236 us; speedup 1.0000x reference)
//
#include <hip/hip_runtime.h>
#include <hip/hip_bf16.h>

// Problem dims
constexpr int NB = 32, NS = 512, NE = 256, NC = 128, NHD = 256, NG = 1024, NT = 16, NH = 512;

typedef float f32x4 __attribute__((ext_vector_type(4)));
typedef short bf16x8 __attribute__((ext_vector_type(8)));
typedef int i32x8 __attribute__((ext_vector_type(8)));
typedef unsigned long long u64x4 __attribute__((ext_vector_type(4)));

#if __has_builtin(__builtin_amdgcn_mfma_scale_f32_16x16x128_f8f6f4)
#define USE_MX 1
#else
#define USE_MX 0
#endif

// ---------------- helpers ----------------
__device__ __forceinline__ unsigned short f2bf(float f) {
    unsigned u = __float_as_uint(f);
    u += 0x7fffu + ((u >> 16) & 1u);
    return (unsigned short)(u >> 16);
}
__device__ __forceinline__ float bf2f(unsigned short s) {
    return __uint_as_float(((unsigned)s) << 16);
}
__device__ __forceinline__ float vexp2(float x) {
    float r; asm("v_exp_f32 %0, %1" : "=v"(r) : "v"(x)); return r;
}
__device__ __forceinline__ float vrcp(float x) {
    float r; asm("v_rcp_f32 %0, %1" : "=v"(r) : "v"(x)); return r;
}
__device__ __forceinline__ float vlog2(float x) {
    float r; asm("v_log_f32 %0, %1" : "=v"(r) : "v"(x)); return r;
}
__device__ __forceinline__ unsigned char f2fp8(float v) {
    int r = __builtin_amdgcn_cvt_pk_fp8_f32(v, 0.f, 0, false);
    return (unsigned char)(r & 0xff);
}
// gate pre-activation scale factors (i,f,o: sigm -> -log2(e); g: tanh -> +2*log2(e))
__device__ __constant__ float KSC[4] = {-1.442695041f, -1.442695041f, 2.885390082f, -1.442695041f};

// ---------------- prep: scale (producer for the merged prep kernel) ----------------
__global__ void k_prep_scale(const float* __restrict__ whh_f, const float* __restrict__ whh_b,
                             float* __restrict__ scale) {
    int d = blockIdx.y;
    const float* src = d ? whh_b : whh_f;
    int col = blockIdx.x * 256 + threadIdx.x;
    if (col >= 1024) return;
    int j = col >> 2, g = col & 3;
    const float* p = src + (size_t)(g * 256 + j) * 256;
    float m = 0.f;
    for (int k = 0; k < 256; ++k) m = fmaxf(m, fabsf(p[k]));
    scale[d * 1024 + col] = (m > 0.f) ? (m * (1.f / 448.f)) : 1.f;
}

// ---------------- merged prep: convw | whh fp8 frags | wih bf16 frags | bias ----------------
// block ranges: [0,384) convw, [384,2432) whh8, [2432,3456) wihF, [3456,3464) bias
__global__ void k_prep_main(const float* __restrict__ conv_w, float* __restrict__ wT,
                            const float* __restrict__ whh_f, const float* __restrict__ whh_b,
                            const float* __restrict__ scale, unsigned char* __restrict__ whhF8,
                            const float* __restrict__ wih_f, const float* __restrict__ wih_b,
                            unsigned short* __restrict__ wihF,
                            const float* __restrict__ bih_f, const float* __restrict__ bhh_f,
                            const float* __restrict__ bih_b, const float* __restrict__ bhh_b,
                            float* __restrict__ bias2s) {
    int blk = blockIdx.x;
    if (blk < 384) {
        int i = blk * 256 + threadIdx.x;
        if (i < 768 * 128) {
            int e3 = i >> 7, c = i & 127;
            wT[i] = conv_w[c * 768 + e3];
        }
    } else if (blk < 2432) {
        int i = (blk - 384) * 256 + threadIdx.x;
#if USE_MX
        // MX K=128 B-frag layout: idx bits e:5 | lane:6 | frag:3 | w:4 | d:1
        // frag = g*2 + n; j = w*16 + (lane&15); k = n*128 + ((lane>>4)&3)*32 + e
        int e = i & 31;
        int lane = (i >> 5) & 63;
        int frag = (i >> 11) & 7;
        int w = (i >> 14) & 15;
        int d = (i >> 18) & 1;
        int g = frag >> 1, n = frag & 1;
        const float* src = d ? whh_b : whh_f;
        int j = w * 16 + (lane & 15);
        int k = n * 128 + ((lane >> 4) & 3) * 32 + e;
        float sc = scale[d * 1024 + j * 4 + g];
        whhF8[i] = f2fp8(src[(g * 256 + j) * 256 + k] / sc);
#else
        // K=32 B-frag layout: idx bits e:3 | lane:6 | g:2 | kt:3 | w:4 | d:1
        int e = i & 7;
        int lane = (i >> 3) & 63;
        int g = (i >> 9) & 3;
        int kt = (i >> 11) & 7;
        int w = (i >> 14) & 15;
        int d = (i >> 18) & 1;
        const float* src = d ? whh_b : whh_f;
        int j = w * 16 + (lane & 15);
        int k = kt * 32 + (lane >> 4) * 8 + e;
        float sc = scale[d * 1024 + j * 4 + g];
        whhF8[i] = f2fp8(src[(g * 256 + j) * 256 + k] / sc);
#endif
    } else if (blk < 3456) {
        int i = (blk - 2432) * 256 + threadIdx.x;
        int e = i & 7;
        int lane = (i >> 3) & 63;
        int kt = (i >> 9) & 3;
        int ctg = (i >> 11) & 63;
        int d = (i >> 17) & 1;
        const float* src = d ? wih_b : wih_f;
        int row = lane & 15;
        int cell = ctg * 4 + (row >> 2), g = row & 3;
        int k = kt * 32 + (lane >> 4) * 8 + e;
        wihF[i] = f2bf(src[(g * 256 + cell) * 128 + k] * KSC[g]);
    } else {
        int i = (blk - 3456) * 256 + threadIdx.x;
        int d = i >> 10;
        int col = i & 1023;
        const float* bi = d ? bih_b : bih_f;
        const float* bh = d ? bhh_b : bhh_f;
        int g = col & 3, j = col >> 2;
        bias2s[(size_t)d * NG + col] = (bi[g * 256 + j] + bh[g * 256 + j]) * KSC[g];
    }
}

// ---------------- embedding + conv1d(k=3,pad=1) + relu -> bf16 feat ----------------
__global__ __launch_bounds__(128) void k_conv(const int* __restrict__ x,
                                              const float* __restrict__ table,
                                              const float* __restrict__ wT,
                                              const float* __restrict__ conv_b,
                                              unsigned short* __restrict__ feat) {
    int b = blockIdx.y;
    int s0 = blockIdx.x * 8;
    int c = threadIdx.x;
    __shared__ float win[10][NE];
    for (int i = 0; i < 10; ++i) {
        int s = s0 - 1 + i;
        if (s < 0 || s >= NS) {
            for (int e = c; e < NE; e += 128) win[i][e] = 0.f;
        } else {
            int tok = x[b * NS + s];
            const float* row = table + (size_t)tok * NE;
            for (int e = c; e < NE; e += 128) win[i][e] = row[e];
        }
    }
    __syncthreads();
    float acc[8];
    float bc = conv_b[c];
#pragma unroll
    for (int p = 0; p < 8; ++p) acc[p] = bc;
    for (int e = 0; e < NE; ++e) {
        float r[10];
#pragma unroll
        for (int i = 0; i < 10; ++i) r[i] = win[i][e];
#pragma unroll
        for (int k = 0; k < 3; ++k) {
            float wv = wT[(e * 3 + k) * NC + c];
#pragma unroll
            for (int p = 0; p < 8; ++p) acc[p] += wv * r[p + k];
        }
    }
#pragma unroll
    for (int p = 0; p < 8; ++p) {
        feat[((size_t)b * NS + s0 + p) * NC + c] = f2bf(fmaxf(acc[p], 0.f));
    }
}

// ---------------- input-side gates via bf16 MFMA, 32 pairs/block ----------------
__global__ __launch_bounds__(256) void k_xgate(const unsigned short* __restrict__ feat,
                                               const unsigned short* __restrict__ wihF,
                                               const float* __restrict__ bias2s,
                                               unsigned short* __restrict__ xg) {
    int d = blockIdx.y;
    int p0 = blockIdx.x * 32;
    int tid = threadIdx.x;
    int w = tid >> 6, l = tid & 63;
    int l15 = l & 15, lq = l >> 4;
    int pA = p0 + l15, pB = p0 + 16 + l15;
    int bA = pA & 31, sA = pA >> 5;
    int bB = pB & 31, sB = pB >> 5;
    const unsigned short* fpA = feat + ((size_t)bA * NS + sA) * NC + lq * 8;
    const unsigned short* fpB = feat + ((size_t)bB * NS + sB) * NC + lq * 8;
    bf16x8 bfA[4], bfB[4];
#pragma unroll
    for (int kt = 0; kt < 4; ++kt) {
        bfA[kt] = *(const bf16x8*)(fpA + kt * 32);
        bfB[kt] = *(const bf16x8*)(fpB + kt * 32);
    }
    const unsigned short* WF = wihF + ((size_t)d << 17);
    unsigned short* XGD = xg + (size_t)d * NS * NB * NG;
#pragma unroll
    for (int ct = 0; ct < 16; ++ct) {
        int ctg = w * 16 + ct;
        int cell = ctg * 4 + lq;
        float4 bv = *(const float4*)(bias2s + (size_t)d * NG + cell * 4);
        f32x4 accA = {bv.x, bv.y, bv.z, bv.w};
        f32x4 accB = accA;
#pragma unroll
        for (int kt = 0; kt < 4; ++kt) {
            bf16x8 af = *(const bf16x8*)(WF + (((size_t)ctg * 4 + kt) * 64 + l) * 8);
            accA = __builtin_amdgcn_mfma_f32_16x16x32_bf16(af, bfA[kt], accA, 0, 0, 0);
            accB = __builtin_amdgcn_mfma_f32_16x16x32_bf16(af, bfB[kt], accB, 0, 0, 0);
        }
        unsigned long long hA = (unsigned long long)f2bf(accA[0])
                              | ((unsigned long long)f2bf(accA[1]) << 16)
                              | ((unsigned long long)f2bf(accA[2]) << 32)
                              | ((unsigned long long)f2bf(accA[3]) << 48);
        unsigned long long hB = (unsigned long long)f2bf(accB[0])
                              | ((unsigned long long)f2bf(accB[1]) << 16)
                              | ((unsigned long long)f2bf(accB[2]) << 32)
                              | ((unsigned long long)f2bf(accB[3]) << 48);
        *(unsigned long long*)(XGD + (size_t)pA * 1024 + cell * 4) = hA;
        *(unsigned long long*)(XGD + (size_t)pB * 1024 + cell * 4) = hB;
    }
}

// ---------------- LSTM recurrence: round-14 structure; MX K=128 MFMA if available ----------
__global__ __launch_bounds__(1024, 1) void k_lstm2(const unsigned char* __restrict__ whhF8,
                                                   const float* __restrict__ scale,
                                                   const unsigned short* __restrict__ xg,
                                                   unsigned short* __restrict__ hcat) {
    int bid = blockIdx.x;
    int d = bid >> 1, bh = bid & 1;
    int tid = threadIdx.x;
    int w = tid >> 6, l = tid & 63;
    int l15 = l & 15, lq = l >> 4;
    __shared__ unsigned char hbuf[2][16][280];
    for (int i = tid; i < 2 * 16 * 280; i += 1024) (&hbuf[0][0][0])[i] = 0;
#if USE_MX
    // preload MX B-frags: 8 frags x 8 VGPRs = 64 regs/thread
    i32x8 wf8[8];
    {
        const unsigned char* wp = whhF8 + ((size_t)(d * 16 + w) << 14) + (size_t)l * 32;
#pragma unroll
        for (int f = 0; f < 8; ++f) wf8[f] = *(const i32x8*)(wp + f * 2048);
    }
#else
    unsigned long long wf[32];
    {
        const unsigned char* wp = whhF8 + ((size_t)(d * 16 + w) << 14) + (size_t)l * 8;
#pragma unroll
        for (int f = 0; f < 32; ++f) wf[f] = *(const unsigned long long*)(wp + f * 512);
    }
#endif
    int cell = w * 16 + l15;
    float csc[4];
#pragma unroll
    for (int g = 0; g < 4; ++g)
        csc[g] = scale[d * 1024 + cell * 4 + g] * KSC[g];
    const unsigned short* XG = xg + (size_t)d * NS * NB * NG;
    float cst[4] = {};
    __syncthreads();
    int cur = 0;
    unsigned long long xq[4];
    {
        int s0 = d ? (NS - 1) : 0;
#pragma unroll
        for (int r = 0; r < 4; ++r)
            xq[r] = *(const unsigned long long*)(
                XG + (size_t)(s0 * 32 + bh * 16 + lq * 4 + r) * 1024 + cell * 4);
    }
    for (int step = 0; step < NS; ++step) {
        int s = d ? (NS - 1 - step) : step;
        unsigned long long xn[4];
        {
            int stn = (step + 1 < NS) ? step + 1 : step;
            int sn = d ? (NS - 1 - stn) : stn;
#pragma unroll
            for (int r = 0; r < 4; ++r)
                xn[r] = *(const unsigned long long*)(
                    XG + (size_t)(sn * 32 + bh * 16 + lq * 4 + r) * 1024 + cell * 4);
        }
        f32x4 acc[4];
#pragma unroll
        for (int g = 0; g < 4; ++g) acc[g] = (f32x4){0.f, 0.f, 0.f, 0.f};
#if USE_MX
        {
            const unsigned char* hrow = &hbuf[cur][l15][0];
#pragma unroll
            for (int n = 0; n < 2; ++n) {
                int base = n * 128 + lq * 32;
                u64x4 t;
                t[0] = *(const unsigned long long*)(hrow + base);
                t[1] = *(const unsigned long long*)(hrow + base + 8);
                t[2] = *(const unsigned long long*)(hrow + base + 16);
                t[3] = *(const unsigned long long*)(hrow + base + 24);
                i32x8 av = __builtin_bit_cast(i32x8, t);
#pragma unroll
                for (int g = 0; g < 4; ++g)
                    acc[g] = __builtin_amdgcn_mfma_scale_f32_16x16x128_f8f6f4(
                        av, wf8[g * 2 + n], acc[g], 0, 0,
                        0, 0x7f7f7f7f, 0, 0x7f7f7f7f);
            }
        }
#else
#pragma unroll
        for (int kt = 0; kt < 8; ++kt) {
            unsigned long long a = *(const unsigned long long*)&hbuf[cur][l15][kt * 32 + lq * 8];
#pragma unroll
            for (int g = 0; g < 4; ++g)
                acc[g] = __builtin_amdgcn_mfma_f32_16x16x32_fp8_fp8(
                    (long long)a, (long long)wf[kt * 4 + g], acc[g], 0, 0, 0);
        }
#endif
        int nxt = cur ^ 1;
#pragma unroll
        for (int r = 0; r < 4; ++r) {
            unsigned long long xv = xq[r];
            float pi = fmaf(acc[0][r], csc[0], bf2f((unsigned short)xv));
            float pf = fmaf(acc[1][r], csc[1], bf2f((unsigned short)(xv >> 16)));
            float pg = fmaf(acc[2][r], csc[2], bf2f((unsigned short)(xv >> 32)));
            float po = fmaf(acc[3][r], csc[3], bf2f((unsigned short)(xv >> 48)));
            float si = vrcp(1.f + vexp2(pi));
            float sf = vrcp(1.f + vexp2(pf));
            float tg = fmaf(-2.f, vrcp(1.f + vexp2(pg)), 1.f);
            float so = vrcp(1.f + vexp2(po));
            float c = fmaf(sf, cst[r], si * tg);
            cst[r] = c;
            float tc = fmaf(-2.f, vrcp(1.f + vexp2(2.885390082f * c)), 1.f);
            float h = so * tc;
            int b = lq * 4 + r;
            __builtin_nontemporal_store(f2bf(h),
                hcat + (size_t)(s * 32 + bh * 16 + b) * NH + d * NHD + cell);
            hbuf[nxt][b][cell] = f2fp8(h);
        }
        __syncthreads();
        cur = nxt;
#pragma unroll
        for (int r = 0; r < 4; ++r) xq[r] = xn[r];
    }
}

// ---------------- FC to emissions: em[s][b][t]  (hcat is bf16) ----------------
__global__ __launch_bounds__(256) void k_fc(const unsigned short* __restrict__ hcat,
                                            const float* __restrict__ fc_w,
                                            const float* __restrict__ fc_b,
                                            float* __restrict__ em) {
    int p0 = blockIdx.x * 16;
    __shared__ float hv[16][NH];
    for (int i = threadIdx.x; i < 16 * NH; i += 256) {
        int p = i >> 9, hh = i & 511;
        hv[p][hh] = bf2f(hcat[(size_t)(p0 + p) * NH + hh]);
    }
    __syncthreads();
    int p = threadIdx.x >> 4, t = threadIdx.x & 15;
    const float* fw = fc_w + t * NH;
    float acc = fc_b[t];
#pragma unroll 8
    for (int hh = 0; hh < NH; ++hh) acc += hv[p][hh] * fw[hh];
    em[(size_t)(p0 + p) * NT + t] = acc;
}

// ---------------- CRF NLL per batch: wave-parallel forward algorithm ----------------
__global__ __launch_bounds__(64) void k_crf(const float* __restrict__ em,
                                            const int* __restrict__ tags,
                                            const int* __restrict__ mask,
                                            const float* __restrict__ start_t,
                                            const float* __restrict__ end_t,
                                            const float* __restrict__ trans,
                                            float* __restrict__ res) {
    int b = blockIdx.x;
    int tid = threadIdx.x;
    __shared__ float em_sh[NS * NT];
    __shared__ float tr[NT * NT];
    __shared__ float alpha_sh[NT];
    __shared__ float msk[NS];
    __shared__ float sc_sh;
    for (int i = tid; i < NT * NT; i += 64) tr[i] = trans[i];
    for (int i = tid; i < NS * NT; i += 64) {
        int s = i >> 4, t = i & 15;
        em_sh[i] = em[((size_t)s * NB + b) * NT + t];
    }
    for (int s = tid; s < NS; s += 64) msk[s] = (float)mask[b * NS + s];
    __syncthreads();
    float part = 0.f, msum = 0.f;
    for (int s = tid; s < NS; s += 64) msum += msk[s];
    for (int s = 1 + tid; s < NS; s += 64) {
        int pv = tags[b * NS + s - 1], cu = tags[b * NS + s];
        part += (tr[pv * NT + cu] + em_sh[s * NT + cu]) * msk[s];
    }
#pragma unroll
    for (int o = 32; o > 0; o >>= 1) {
        part += __shfl_down(part, o);
        msum += __shfl_down(msum, o);
    }
    if (tid == 0) {
        int t0 = tags[b * NS];
        int send = (int)msum - 1;
        sc_sh = start_t[t0] + em_sh[t0] + part + end_t[tags[b * NS + send]];
    }
    if (tid < NT) alpha_sh[tid] = start_t[tid] + em_sh[tid];
    __syncthreads();
    int t_to = tid >> 2, q = tid & 3;
    for (int s = 1; s < NS; ++s) {
        float v0 = alpha_sh[q * 4 + 0] + tr[(q * 4 + 0) * NT + t_to];
        float v1 = alpha_sh[q * 4 + 1] + tr[(q * 4 + 1) * NT + t_to];
        float v2 = alpha_sh[q * 4 + 2] + tr[(q * 4 + 2) * NT + t_to];
        float v3 = alpha_sh[q * 4 + 3] + tr[(q * 4 + 3) * NT + t_to];
        float mx = fmaxf(fmaxf(v0, v1), fmaxf(v2, v3));
        mx = fmaxf(mx, __shfl_xor(mx, 1));
        mx = fmaxf(mx, __shfl_xor(mx, 2));
        float nmx = -1.442695041f * mx;
        float ss = vexp2(fmaf(v0, 1.442695041f, nmx)) + vexp2(fmaf(v1, 1.442695041f, nmx))
                 + vexp2(fmaf(v2, 1.442695041f, nmx)) + vexp2(fmaf(v3, 1.442695041f, nmx));
        ss += __shfl_xor(ss, 1);
        ss += __shfl_xor(ss, 2);
        float nv = mx + 0.6931471806f * vlog2(ss) + em_sh[s * NT + t_to];
        float old = alpha_sh[t_to];
        nv = (msk[s] > 0.f) ? nv : old;
        __syncthreads();
        if (q == 0) alpha_sh[t_to] = nv;
        __syncthreads();
    }
    if (tid == 0) {
        float mx = -1e30f;
        for (int t = 0; t < NT; ++t) mx = fmaxf(mx, alpha_sh[t] + end_t[t]);
        float sum = 0.f;
        for (int t = 0; t < NT; ++t) sum += vexp2(1.442695041f * (alpha_sh[t] + end_t[t] - mx));
        res[b] = sc_sh - (mx + 0.6931471806f * vlog2(sum));
    }
}

__global__ void k_final(const float* __restrict__ res, float* __restrict__ out) {
    int tid = threadIdx.x;
    float v = (tid < NB) ? res[tid] : 0.f;
#pragma unroll
    for (int o = 32; o > 0; o >>= 1) v += __shfl_down(v, o);
    if (tid == 0) out[0] = -v / NB;
}

// ---------------- workspace layout ----------------
constexpr size_t SZ_FEAT  = (size_t)NB * NS * NC * 2;       // 4 MB (bf16)
constexpr size_t SZ_WT    = (size_t)768 * 128 * 4;          // 384 KB
constexpr size_t SZ_WHHF8 = (size_t)(1 << 19);              // 512 KB (fp8 frags)
constexpr size_t SZ_SCALE = (size_t)2 * 1024 * 4;           // 8 KB
constexpr size_t SZ_WIHF  = (size_t)(1 << 18) * 2;          // 512 KB (bf16 A-frags)
constexpr size_t SZ_BIAS  = (size_t)2 * NG * 4;             // 8 KB
constexpr size_t SZ_XG    = (size_t)2 * NS * NB * NG * 2;   // 64 MB (bf16)
constexpr size_t SZ_HCAT  = (size_t)NS * NB * NH * 2;       // 16 MB (bf16)
constexpr size_t SZ_EM    = (size_t)NS * NB * NT * 4;       // 1 MB

constexpr size_t OFF_FEAT  = 0;
constexpr size_t OFF_WT    = OFF_FEAT + SZ_FEAT;
constexpr size_t OFF_WHHF8 = OFF_WT + SZ_WT;
constexpr size_t OFF_SCALE = OFF_WHHF8 + SZ_WHHF8;
constexpr size_t OFF_WIHF  = OFF_SCALE + SZ_SCALE;
constexpr size_t OFF_BIAS  = OFF_WIHF + SZ_WIHF;
constexpr size_t OFF_XG    = OFF_BIAS + SZ_BIAS;
constexpr size_t OFF_HCAT  = OFF_XG + SZ_XG;
constexpr size_t OFF_EM    = OFF_HCAT + SZ_HCAT;
constexpr size_t OFF_RES   = OFF_EM + SZ_EM;

extern "C" void kernel_launch(void* const* d_in, const int* in_sizes, int n_in,
                              void* d_out, int out_size, void* d_ws, size_t ws_size,
                              hipStream_t stream) {
    const int* x        = (const int*)d_in[0];
    const int* mask     = (const int*)d_in[1];
    const int* tags     = (const int*)d_in[2];
    const float* table  = (const float*)d_in[3];
    const float* conv_w = (const float*)d_in[4];
    const float* conv_b = (const float*)d_in[5];
    const float* wih_f  = (const float*)d_in[6];
    const float* whh_f  = (const float*)d_in[7];
    const float* bih_f  = (const float*)d_in[8];
    const float* bhh_f  = (const float*)d_in[9];
    const float* wih_b  = (const float*)d_in[10];
    const float* whh_b  = (const float*)d_in[11];
    const float* bih_b  = (const float*)d_in[12];
    const float* bhh_b  = (const float*)d_in[13];
    const float* fc_w   = (const float*)d_in[14];
    const float* fc_b   = (const float*)d_in[15];
    const float* start_t = (const float*)d_in[16];
    const float* end_t  = (const float*)d_in[17];
    const float* trans  = (const float*)d_in[18];

    char* ws = (char*)d_ws;
    unsigned short* feat = (unsigned short*)(ws + OFF_FEAT);
    float* wT   = (float*)(ws + OFF_WT);
    unsigned char* whhF8 = (unsigned char*)(ws + OFF_WHHF8);
    float* scale = (float*)(ws + OFF_SCALE);
    unsigned short* wihF = (unsigned short*)(ws + OFF_WIHF);
    float* bias2s = (float*)(ws + OFF_BIAS);
    unsigned short* xg = (unsigned short*)(ws + OFF_XG);
    unsigned short* hcat = (unsigned short*)(ws + OFF_HCAT);
    float* em   = (float*)(ws + OFF_EM);
    float* res  = (float*)(ws + OFF_RES);

    k_prep_scale<<<dim3(4, 2), 256, 0, stream>>>(whh_f, whh_b, scale);
    k_prep_main<<<dim3(3464), 256, 0, stream>>>(conv_w, wT, whh_f, whh_b, scale, whhF8,
                                                wih_f, wih_b, wihF,
                                                bih_f, bhh_f, bih_b, bhh_b, bias2s);
    k_conv<<<dim3(NS / 8, NB), 128, 0, stream>>>(x, table, wT, conv_b, feat);
    k_xgate<<<dim3(NS * NB / 32, 2), 256, 0, stream>>>(feat, wihF, bias2s, xg);
    k_lstm2<<<dim3(4), 1024, 0, stream>>>(whhF8, scale, xg, hcat);
    k_fc<<<dim3(NS * NB / 16), 256, 0, stream>>>(hcat, fc_w, fc_b, em);
    k_crf<<<dim3(NB), 64, 0, stream>>>(em, tags, mask, start_t, end_t, trans, res);
    k_final<<<dim3(1), 64, 0, stream>>>(res, (float*)d_out);
}

// Round 17
// 1293.443 us; speedup vs baseline: 1.4653x; 1.4653x over previous
//
#include <hip/hip_runtime.h>
#include <hip/hip_bf16.h>

// Problem dims
constexpr int NB = 32, NS = 512, NE = 256, NC = 128, NHD = 256, NG = 1024, NT = 16, NH = 512;

typedef float f32x4 __attribute__((ext_vector_type(4)));
typedef short bf16x8 __attribute__((ext_vector_type(8)));

// ---------------- helpers ----------------
__device__ __forceinline__ unsigned short f2bf(float f) {
    unsigned u = __float_as_uint(f);
    u += 0x7fffu + ((u >> 16) & 1u);
    return (unsigned short)(u >> 16);
}
__device__ __forceinline__ float bf2f(unsigned short s) {
    return __uint_as_float(((unsigned)s) << 16);
}
__device__ __forceinline__ float vexp2(float x) {
    float r; asm("v_exp_f32 %0, %1" : "=v"(r) : "v"(x)); return r;
}
__device__ __forceinline__ float vrcp(float x) {
    float r; asm("v_rcp_f32 %0, %1" : "=v"(r) : "v"(x)); return r;
}
__device__ __forceinline__ float vlog2(float x) {
    float r; asm("v_log_f32 %0, %1" : "=v"(r) : "v"(x)); return r;
}
__device__ __forceinline__ unsigned char f2fp8(float v) {
    int r = __builtin_amdgcn_cvt_pk_fp8_f32(v, 0.f, 0, false);
    return (unsigned char)(r & 0xff);
}
// gate pre-activation scale factors (i,f,o: sigm -> -log2(e); g: tanh -> +2*log2(e))
__device__ __constant__ float KSC[4] = {-1.442695041f, -1.442695041f, 2.885390082f, -1.442695041f};

// ---------------- prep: scale (producer for the merged prep kernel) ----------------
__global__ void k_prep_scale(const float* __restrict__ whh_f, const float* __restrict__ whh_b,
                             float* __restrict__ scale) {
    int d = blockIdx.y;
    const float* src = d ? whh_b : whh_f;
    int col = blockIdx.x * 256 + threadIdx.x;
    if (col >= 1024) return;
    int j = col >> 2, g = col & 3;
    const float* p = src + (size_t)(g * 256 + j) * 256;
    float m = 0.f;
    for (int k = 0; k < 256; ++k) m = fmaxf(m, fabsf(p[k]));
    scale[d * 1024 + col] = (m > 0.f) ? (m * (1.f / 448.f)) : 1.f;
}

// ---------------- merged prep: convw | whh fp8 frags | wih bf16 frags | bias | fcw frags ----
// block ranges: [0,384) convw, [384,2432) whh8, [2432,3456) wihF, [3456,3464) bias,
//               [3464,3496) fcwF
__global__ void k_prep_main(const float* __restrict__ conv_w, float* __restrict__ wT,
                            const float* __restrict__ whh_f, const float* __restrict__ whh_b,
                            const float* __restrict__ scale, unsigned char* __restrict__ whhF8,
                            const float* __restrict__ wih_f, const float* __restrict__ wih_b,
                            unsigned short* __restrict__ wihF,
                            const float* __restrict__ bih_f, const float* __restrict__ bhh_f,
                            const float* __restrict__ bih_b, const float* __restrict__ bhh_b,
                            float* __restrict__ bias2s,
                            const float* __restrict__ fc_w, unsigned short* __restrict__ fcwF) {
    int blk = blockIdx.x;
    if (blk < 384) {
        int i = blk * 256 + threadIdx.x;
        if (i < 768 * 128) {
            int e3 = i >> 7, c = i & 127;
            wT[i] = conv_w[c * 768 + e3];
        }
    } else if (blk < 2432) {
        // K=32 fp8 B-frag layout: idx bits e:3 | lane:6 | g:2 | kt:3 | w:4 | d:1
        int i = (blk - 384) * 256 + threadIdx.x;
        int e = i & 7;
        int lane = (i >> 3) & 63;
        int g = (i >> 9) & 3;
        int kt = (i >> 11) & 7;
        int w = (i >> 14) & 15;
        int d = (i >> 18) & 1;
        const float* src = d ? whh_b : whh_f;
        int j = w * 16 + (lane & 15);
        int k = kt * 32 + (lane >> 4) * 8 + e;
        float sc = scale[d * 1024 + j * 4 + g];
        whhF8[i] = f2fp8(src[(g * 256 + j) * 256 + k] / sc);
    } else if (blk < 3456) {
        int i = (blk - 2432) * 256 + threadIdx.x;
        int e = i & 7;
        int lane = (i >> 3) & 63;
        int kt = (i >> 9) & 3;
        int ctg = (i >> 11) & 63;
        int d = (i >> 17) & 1;
        const float* src = d ? wih_b : wih_f;
        int row = lane & 15;
        int cell = ctg * 4 + (row >> 2), g = row & 3;
        int k = kt * 32 + (lane >> 4) * 8 + e;
        wihF[i] = f2bf(src[(g * 256 + cell) * 128 + k] * KSC[g]);
    } else if (blk < 3464) {
        int i = (blk - 3456) * 256 + threadIdx.x;
        int d = i >> 10;
        int col = i & 1023;
        const float* bi = d ? bih_b : bih_f;
        const float* bh = d ? bhh_b : bhh_f;
        int g = col & 3, j = col >> 2;
        bias2s[(size_t)d * NG + col] = (bi[g * 256 + j] + bh[g * 256 + j]) * KSC[g];
    } else {
        // fc_w^T bf16 B-frags: idx = (kt*64 + lane)*8 + e; n = lane&15, k = kt*32+(lane>>4)*8+e
        int i = (blk - 3464) * 256 + threadIdx.x;
        if (i < 8192) {
            int e = i & 7;
            int lane = (i >> 3) & 63;
            int kt = (i >> 9) & 15;
            int n = lane & 15;
            int k = kt * 32 + (lane >> 4) * 8 + e;
            fcwF[i] = f2bf(fc_w[n * NH + k]);
        }
    }
}

// ---------------- embedding + conv1d(k=3,pad=1) + relu -> bf16 feat ----------------
__global__ __launch_bounds__(128) void k_conv(const int* __restrict__ x,
                                              const float* __restrict__ table,
                                              const float* __restrict__ wT,
                                              const float* __restrict__ conv_b,
                                              unsigned short* __restrict__ feat) {
    int b = blockIdx.y;
    int s0 = blockIdx.x * 8;
    int c = threadIdx.x;
    __shared__ float win[10][NE];
    for (int i = 0; i < 10; ++i) {
        int s = s0 - 1 + i;
        if (s < 0 || s >= NS) {
            for (int e = c; e < NE; e += 128) win[i][e] = 0.f;
        } else {
            int tok = x[b * NS + s];
            const float* row = table + (size_t)tok * NE;
            for (int e = c; e < NE; e += 128) win[i][e] = row[e];
        }
    }
    __syncthreads();
    float acc[8];
    float bc = conv_b[c];
#pragma unroll
    for (int p = 0; p < 8; ++p) acc[p] = bc;
    for (int e = 0; e < NE; ++e) {
        float r[10];
#pragma unroll
        for (int i = 0; i < 10; ++i) r[i] = win[i][e];
#pragma unroll
        for (int k = 0; k < 3; ++k) {
            float wv = wT[(e * 3 + k) * NC + c];
#pragma unroll
            for (int p = 0; p < 8; ++p) acc[p] += wv * r[p + k];
        }
    }
#pragma unroll
    for (int p = 0; p < 8; ++p) {
        feat[((size_t)b * NS + s0 + p) * NC + c] = f2bf(fmaxf(acc[p], 0.f));
    }
}

// ---------------- input-side gates via bf16 MFMA, 32 pairs/block ----------------
__global__ __launch_bounds__(256) void k_xgate(const unsigned short* __restrict__ feat,
                                               const unsigned short* __restrict__ wihF,
                                               const float* __restrict__ bias2s,
                                               unsigned short* __restrict__ xg) {
    int d = blockIdx.y;
    int p0 = blockIdx.x * 32;
    int tid = threadIdx.x;
    int w = tid >> 6, l = tid & 63;
    int l15 = l & 15, lq = l >> 4;
    int pA = p0 + l15, pB = p0 + 16 + l15;
    int bA = pA & 31, sA = pA >> 5;
    int bB = pB & 31, sB = pB >> 5;
    const unsigned short* fpA = feat + ((size_t)bA * NS + sA) * NC + lq * 8;
    const unsigned short* fpB = feat + ((size_t)bB * NS + sB) * NC + lq * 8;
    bf16x8 bfA[4], bfB[4];
#pragma unroll
    for (int kt = 0; kt < 4; ++kt) {
        bfA[kt] = *(const bf16x8*)(fpA + kt * 32);
        bfB[kt] = *(const bf16x8*)(fpB + kt * 32);
    }
    const unsigned short* WF = wihF + ((size_t)d << 17);
    unsigned short* XGD = xg + (size_t)d * NS * NB * NG;
#pragma unroll
    for (int ct = 0; ct < 16; ++ct) {
        int ctg = w * 16 + ct;
        int cell = ctg * 4 + lq;
        float4 bv = *(const float4*)(bias2s + (size_t)d * NG + cell * 4);
        f32x4 accA = {bv.x, bv.y, bv.z, bv.w};
        f32x4 accB = accA;
#pragma unroll
        for (int kt = 0; kt < 4; ++kt) {
            bf16x8 af = *(const bf16x8*)(WF + (((size_t)ctg * 4 + kt) * 64 + l) * 8);
            accA = __builtin_amdgcn_mfma_f32_16x16x32_bf16(af, bfA[kt], accA, 0, 0, 0);
            accB = __builtin_amdgcn_mfma_f32_16x16x32_bf16(af, bfB[kt], accB, 0, 0, 0);
        }
        unsigned long long hA = (unsigned long long)f2bf(accA[0])
                              | ((unsigned long long)f2bf(accA[1]) << 16)
                              | ((unsigned long long)f2bf(accA[2]) << 32)
                              | ((unsigned long long)f2bf(accA[3]) << 48);
        unsigned long long hB = (unsigned long long)f2bf(accB[0])
                              | ((unsigned long long)f2bf(accB[1]) << 16)
                              | ((unsigned long long)f2bf(accB[2]) << 32)
                              | ((unsigned long long)f2bf(accB[3]) << 48);
        *(unsigned long long*)(XGD + (size_t)pA * 1024 + cell * 4) = hA;
        *(unsigned long long*)(XGD + (size_t)pB * 1024 + cell * 4) = hB;
    }
}

// ---------------- LSTM recurrence: fp8 MFMA K=32, W register-resident (round-14 exact) ------
__global__ __launch_bounds__(1024, 1) void k_lstm2(const unsigned char* __restrict__ whhF8,
                                                   const float* __restrict__ scale,
                                                   const unsigned short* __restrict__ xg,
                                                   unsigned short* __restrict__ hcat) {
    int bid = blockIdx.x;
    int d = bid >> 1, bh = bid & 1;
    int tid = threadIdx.x;
    int w = tid >> 6, l = tid & 63;
    int l15 = l & 15, lq = l >> 4;
    __shared__ unsigned char hbuf[2][16][280];
    for (int i = tid; i < 2 * 16 * 280; i += 1024) (&hbuf[0][0][0])[i] = 0;
    unsigned long long wf[32];
    const unsigned char* wp = whhF8 + ((size_t)(d * 16 + w) << 14) + (size_t)l * 8;
#pragma unroll
    for (int f = 0; f < 32; ++f) wf[f] = *(const unsigned long long*)(wp + f * 512);
    int cell = w * 16 + l15;
    float csc[4];
#pragma unroll
    for (int g = 0; g < 4; ++g)
        csc[g] = scale[d * 1024 + cell * 4 + g] * KSC[g];
    const unsigned short* XG = xg + (size_t)d * NS * NB * NG;
    float cst[4] = {};
    __syncthreads();
    int cur = 0;
    unsigned long long xq[4];
    {
        int s0 = d ? (NS - 1) : 0;
#pragma unroll
        for (int r = 0; r < 4; ++r)
            xq[r] = *(const unsigned long long*)(
                XG + (size_t)(s0 * 32 + bh * 16 + lq * 4 + r) * 1024 + cell * 4);
    }
    for (int step = 0; step < NS; ++step) {
        int s = d ? (NS - 1 - step) : step;
        unsigned long long xn[4];
        {
            int stn = (step + 1 < NS) ? step + 1 : step;
            int sn = d ? (NS - 1 - stn) : stn;
#pragma unroll
            for (int r = 0; r < 4; ++r)
                xn[r] = *(const unsigned long long*)(
                    XG + (size_t)(sn * 32 + bh * 16 + lq * 4 + r) * 1024 + cell * 4);
        }
        f32x4 acc[4];
#pragma unroll
        for (int g = 0; g < 4; ++g) acc[g] = (f32x4){0.f, 0.f, 0.f, 0.f};
#pragma unroll
        for (int kt = 0; kt < 8; ++kt) {
            unsigned long long a = *(const unsigned long long*)&hbuf[cur][l15][kt * 32 + lq * 8];
#pragma unroll
            for (int g = 0; g < 4; ++g)
                acc[g] = __builtin_amdgcn_mfma_f32_16x16x32_fp8_fp8(
                    (long long)a, (long long)wf[kt * 4 + g], acc[g], 0, 0, 0);
        }
        int nxt = cur ^ 1;
#pragma unroll
        for (int r = 0; r < 4; ++r) {
            unsigned long long xv = xq[r];
            float pi = fmaf(acc[0][r], csc[0], bf2f((unsigned short)xv));
            float pf = fmaf(acc[1][r], csc[1], bf2f((unsigned short)(xv >> 16)));
            float pg = fmaf(acc[2][r], csc[2], bf2f((unsigned short)(xv >> 32)));
            float po = fmaf(acc[3][r], csc[3], bf2f((unsigned short)(xv >> 48)));
            float si = vrcp(1.f + vexp2(pi));
            float sf = vrcp(1.f + vexp2(pf));
            float tg = fmaf(-2.f, vrcp(1.f + vexp2(pg)), 1.f);
            float so = vrcp(1.f + vexp2(po));
            float c = fmaf(sf, cst[r], si * tg);
            cst[r] = c;
            float tc = fmaf(-2.f, vrcp(1.f + vexp2(2.885390082f * c)), 1.f);
            float h = so * tc;
            int b = lq * 4 + r;
            __builtin_nontemporal_store(f2bf(h),
                hcat + (size_t)(s * 32 + bh * 16 + b) * NH + d * NHD + cell);
            hbuf[nxt][b][cell] = f2fp8(h);
        }
        __syncthreads();
        cur = nxt;
#pragma unroll
        for (int r = 0; r < 4; ++r) xq[r] = xn[r];
    }
}

// ---------------- FC to emissions via bf16 MFMA: em[p][t], M=pairs N=16 K=512 ----------------
// Wave handles 16 pairs; A = hcat rows (bf16, direct), B = fcwF frags; 16 MFMA.
// C-layout: col=lane&15=tag, row=(lane>>4)*4+r=pair-in-tile.
__global__ __launch_bounds__(256) void k_fc(const unsigned short* __restrict__ hcat,
                                            const unsigned short* __restrict__ fcwF,
                                            const float* __restrict__ fc_b,
                                            float* __restrict__ em) {
    int tid = threadIdx.x;
    int w = tid >> 6, l = tid & 63;
    int l15 = l & 15, lq = l >> 4;
    int p0 = blockIdx.x * 64 + w * 16;
    bf16x8 bfr[16];
#pragma unroll
    for (int kt = 0; kt < 16; ++kt)
        bfr[kt] = *(const bf16x8*)(fcwF + ((size_t)kt * 64 + l) * 8);
    const unsigned short* hp = hcat + (size_t)(p0 + l15) * NH + lq * 8;
    f32x4 acc = {0.f, 0.f, 0.f, 0.f};
#pragma unroll
    for (int kt = 0; kt < 16; ++kt) {
        bf16x8 af = *(const bf16x8*)(hp + kt * 32);
        acc = __builtin_amdgcn_mfma_f32_16x16x32_bf16(af, bfr[kt], acc, 0, 0, 0);
    }
    float bias = fc_b[l15];
#pragma unroll
    for (int r = 0; r < 4; ++r)
        em[(size_t)(p0 + lq * 4 + r) * NT + l15] = acc[r] + bias;
}

// ---------------- CRF NLL per batch: wave-parallel forward algorithm ----------------
__global__ __launch_bounds__(64) void k_crf(const float* __restrict__ em,
                                            const int* __restrict__ tags,
                                            const int* __restrict__ mask,
                                            const float* __restrict__ start_t,
                                            const float* __restrict__ end_t,
                                            const float* __restrict__ trans,
                                            float* __restrict__ res) {
    int b = blockIdx.x;
    int tid = threadIdx.x;
    __shared__ float em_sh[NS * NT];
    __shared__ float tr[NT * NT];
    __shared__ float alpha_sh[NT];
    __shared__ float msk[NS];
    __shared__ float sc_sh;
    for (int i = tid; i < NT * NT; i += 64) tr[i] = trans[i];
    for (int i = tid; i < NS * NT; i += 64) {
        int s = i >> 4, t = i & 15;
        em_sh[i] = em[((size_t)s * NB + b) * NT + t];
    }
    for (int s = tid; s < NS; s += 64) msk[s] = (float)mask[b * NS + s];
    __syncthreads();
    float part = 0.f, msum = 0.f;
    for (int s = tid; s < NS; s += 64) msum += msk[s];
    for (int s = 1 + tid; s < NS; s += 64) {
        int pv = tags[b * NS + s - 1], cu = tags[b * NS + s];
        part += (tr[pv * NT + cu] + em_sh[s * NT + cu]) * msk[s];
    }
#pragma unroll
    for (int o = 32; o > 0; o >>= 1) {
        part += __shfl_down(part, o);
        msum += __shfl_down(msum, o);
    }
    if (tid == 0) {
        int t0 = tags[b * NS];
        int send = (int)msum - 1;
        sc_sh = start_t[t0] + em_sh[t0] + part + end_t[tags[b * NS + send]];
    }
    if (tid < NT) alpha_sh[tid] = start_t[tid] + em_sh[tid];
    __syncthreads();
    int t_to = tid >> 2, q = tid & 3;
    for (int s = 1; s < NS; ++s) {
        float v0 = alpha_sh[q * 4 + 0] + tr[(q * 4 + 0) * NT + t_to];
        float v1 = alpha_sh[q * 4 + 1] + tr[(q * 4 + 1) * NT + t_to];
        float v2 = alpha_sh[q * 4 + 2] + tr[(q * 4 + 2) * NT + t_to];
        float v3 = alpha_sh[q * 4 + 3] + tr[(q * 4 + 3) * NT + t_to];
        float mx = fmaxf(fmaxf(v0, v1), fmaxf(v2, v3));
        mx = fmaxf(mx, __shfl_xor(mx, 1));
        mx = fmaxf(mx, __shfl_xor(mx, 2));
        float nmx = -1.442695041f * mx;
        float ss = vexp2(fmaf(v0, 1.442695041f, nmx)) + vexp2(fmaf(v1, 1.442695041f, nmx))
                 + vexp2(fmaf(v2, 1.442695041f, nmx)) + vexp2(fmaf(v3, 1.442695041f, nmx));
        ss += __shfl_xor(ss, 1);
        ss += __shfl_xor(ss, 2);
        float nv = mx + 0.6931471806f * vlog2(ss) + em_sh[s * NT + t_to];
        float old = alpha_sh[t_to];
        nv = (msk[s] > 0.f) ? nv : old;
        __syncthreads();
        if (q == 0) alpha_sh[t_to] = nv;
        __syncthreads();
    }
    if (tid == 0) {
        float mx = -1e30f;
        for (int t = 0; t < NT; ++t) mx = fmaxf(mx, alpha_sh[t] + end_t[t]);
        float sum = 0.f;
        for (int t = 0; t < NT; ++t) sum += vexp2(1.442695041f * (alpha_sh[t] + end_t[t] - mx));
        res[b] = sc_sh - (mx + 0.6931471806f * vlog2(sum));
    }
}

__global__ void k_final(const float* __restrict__ res, float* __restrict__ out) {
    int tid = threadIdx.x;
    float v = (tid < NB) ? res[tid] : 0.f;
#pragma unroll
    for (int o = 32; o > 0; o >>= 1) v += __shfl_down(v, o);
    if (tid == 0) out[0] = -v / NB;
}

// ---------------- workspace layout ----------------
constexpr size_t SZ_FEAT  = (size_t)NB * NS * NC * 2;       // 4 MB (bf16)
constexpr size_t SZ_WT    = (size_t)768 * 128 * 4;          // 384 KB
constexpr size_t SZ_WHHF8 = (size_t)(1 << 19);              // 512 KB (fp8 frags)
constexpr size_t SZ_SCALE = (size_t)2 * 1024 * 4;           // 8 KB
constexpr size_t SZ_WIHF  = (size_t)(1 << 18) * 2;          // 512 KB (bf16 A-frags)
constexpr size_t SZ_BIAS  = (size_t)2 * NG * 4;             // 8 KB
constexpr size_t SZ_FCWF  = (size_t)8192 * 2;               // 16 KB (bf16 B-frags)
constexpr size_t SZ_XG    = (size_t)2 * NS * NB * NG * 2;   // 64 MB (bf16)
constexpr size_t SZ_HCAT  = (size_t)NS * NB * NH * 2;       // 16 MB (bf16)
constexpr size_t SZ_EM    = (size_t)NS * NB * NT * 4;       // 1 MB

constexpr size_t OFF_FEAT  = 0;
constexpr size_t OFF_WT    = OFF_FEAT + SZ_FEAT;
constexpr size_t OFF_WHHF8 = OFF_WT + SZ_WT;
constexpr size_t OFF_SCALE = OFF_WHHF8 + SZ_WHHF8;
constexpr size_t OFF_WIHF  = OFF_SCALE + SZ_SCALE;
constexpr size_t OFF_BIAS  = OFF_WIHF + SZ_WIHF;
constexpr size_t OFF_FCWF  = OFF_BIAS + SZ_BIAS;
constexpr size_t OFF_XG    = OFF_FCWF + SZ_FCWF;
constexpr size_t OFF_HCAT  = OFF_XG + SZ_XG;
constexpr size_t OFF_EM    = OFF_HCAT + SZ_HCAT;
constexpr size_t OFF_RES   = OFF_EM + SZ_EM;

extern "C" void kernel_launch(void* const* d_in, const int* in_sizes, int n_in,
                              void* d_out, int out_size, void* d_ws, size_t ws_size,
                              hipStream_t stream) {
    const int* x        = (const int*)d_in[0];
    const int* mask     = (const int*)d_in[1];
    const int* tags     = (const int*)d_in[2];
    const float* table  = (const float*)d_in[3];
    const float* conv_w = (const float*)d_in[4];
    const float* conv_b = (const float*)d_in[5];
    const float* wih_f  = (const float*)d_in[6];
    const float* whh_f  = (const float*)d_in[7];
    const float* bih_f  = (const float*)d_in[8];
    const float* bhh_f  = (const float*)d_in[9];
    const float* wih_b  = (const float*)d_in[10];
    const float* whh_b  = (const float*)d_in[11];
    const float* bih_b  = (const float*)d_in[12];
    const float* bhh_b  = (const float*)d_in[13];
    const float* fc_w   = (const float*)d_in[14];
    const float* fc_b   = (const float*)d_in[15];
    const float* start_t = (const float*)d_in[16];
    const float* end_t  = (const float*)d_in[17];
    const float* trans  = (const float*)d_in[18];

    char* ws = (char*)d_ws;
    unsigned short* feat = (unsigned short*)(ws + OFF_FEAT);
    float* wT   = (float*)(ws + OFF_WT);
    unsigned char* whhF8 = (unsigned char*)(ws + OFF_WHHF8);
    float* scale = (float*)(ws + OFF_SCALE);
    unsigned short* wihF = (unsigned short*)(ws + OFF_WIHF);
    float* bias2s = (float*)(ws + OFF_BIAS);
    unsigned short* fcwF = (unsigned short*)(ws + OFF_FCWF);
    unsigned short* xg = (unsigned short*)(ws + OFF_XG);
    unsigned short* hcat = (unsigned short*)(ws + OFF_HCAT);
    float* em   = (float*)(ws + OFF_EM);
    float* res  = (float*)(ws + OFF_RES);

    k_prep_scale<<<dim3(4, 2), 256, 0, stream>>>(whh_f, whh_b, scale);
    k_prep_main<<<dim3(3496), 256, 0, stream>>>(conv_w, wT, whh_f, whh_b, scale, whhF8,
                                                wih_f, wih_b, wihF,
                                                bih_f, bhh_f, bih_b, bhh_b, bias2s,
                                                fc_w, fcwF);
    k_conv<<<dim3(NS / 8, NB), 128, 0, stream>>>(x, table, wT, conv_b, feat);
    k_xgate<<<dim3(NS * NB / 32, 2), 256, 0, stream>>>(feat, wihF, bias2s, xg);
    k_lstm2<<<dim3(4), 1024, 0, stream>>>(whhF8, scale, xg, hcat);
    k_fc<<<dim3(NS * NB / 64), 256, 0, stream>>>(hcat, fcwF, fc_b, em);
    k_crf<<<dim3(NB), 64, 0, stream>>>(em, tags, mask, start_t, end_t, trans, res);
    k_final<<<dim3(1), 64, 0, stream>>>(res, (float*)d_out);
}

// Round 18
// 1275.982 us; speedup vs baseline: 1.4853x; 1.0137x over previous
//
#include <hip/hip_runtime.h>
#include <hip/hip_bf16.h>

// Problem dims
constexpr int NB = 32, NS = 512, NE = 256, NC = 128, NHD = 256, NG = 1024, NT = 16, NH = 512;

typedef float f32x4 __attribute__((ext_vector_type(4)));
typedef short bf16x8 __attribute__((ext_vector_type(8)));

// ---------------- helpers ----------------
__device__ __forceinline__ unsigned short f2bf(float f) {
    unsigned u = __float_as_uint(f);
    u += 0x7fffu + ((u >> 16) & 1u);
    return (unsigned short)(u >> 16);
}
__device__ __forceinline__ float bf2f(unsigned short s) {
    return __uint_as_float(((unsigned)s) << 16);
}
__device__ __forceinline__ float vexp2(float x) {
    float r; asm("v_exp_f32 %0, %1" : "=v"(r) : "v"(x)); return r;
}
__device__ __forceinline__ float vrcp(float x) {
    float r; asm("v_rcp_f32 %0, %1" : "=v"(r) : "v"(x)); return r;
}
__device__ __forceinline__ float vlog2(float x) {
    float r; asm("v_log_f32 %0, %1" : "=v"(r) : "v"(x)); return r;
}
__device__ __forceinline__ unsigned char f2fp8(float v) {
    int r = __builtin_amdgcn_cvt_pk_fp8_f32(v, 0.f, 0, false);
    return (unsigned char)(r & 0xff);
}
// gate pre-activation scale factors (i,f,o: sigm -> -log2(e); g: tanh -> +2*log2(e))
__device__ __constant__ float KSC[4] = {-1.442695041f, -1.442695041f, 2.885390082f, -1.442695041f};

// ---------------- prep: per-column absmax scale, wave-per-column coalesced ----------------
// grid = (256, 2): block handles 4 columns (one per wave); lane reads k = lane*4..lane*4+3
// contiguous (float4), then shfl-reduce max. Replaces the round-17 version whose
// per-thread serial stride-1KB loop cost ~60 us.
__global__ __launch_bounds__(256) void k_prep_scale(const float* __restrict__ whh_f,
                                                    const float* __restrict__ whh_b,
                                                    float* __restrict__ scale) {
    int d = blockIdx.y;
    const float* src = d ? whh_b : whh_f;
    int w = threadIdx.x >> 6, l = threadIdx.x & 63;
    int col = blockIdx.x * 4 + w;  // 0..1023
    int j = col >> 2, g = col & 3;
    const float* p = src + (size_t)(g * 256 + j) * 256 + l * 4;
    float4 v = *(const float4*)p;
    float m = fmaxf(fmaxf(fabsf(v.x), fabsf(v.y)), fmaxf(fabsf(v.z), fabsf(v.w)));
#pragma unroll
    for (int o = 32; o > 0; o >>= 1) m = fmaxf(m, __shfl_xor(m, o));
    if (l == 0) scale[d * 1024 + col] = (m > 0.f) ? (m * (1.f / 448.f)) : 1.f;
}

// ---------------- merged prep: convw | whh fp8 frags | wih bf16 frags | bias | fcw frags ----
// block ranges: [0,384) convw, [384,2432) whh8, [2432,3456) wihF, [3456,3464) bias,
//               [3464,3496) fcwF
__global__ void k_prep_main(const float* __restrict__ conv_w, float* __restrict__ wT,
                            const float* __restrict__ whh_f, const float* __restrict__ whh_b,
                            const float* __restrict__ scale, unsigned char* __restrict__ whhF8,
                            const float* __restrict__ wih_f, const float* __restrict__ wih_b,
                            unsigned short* __restrict__ wihF,
                            const float* __restrict__ bih_f, const float* __restrict__ bhh_f,
                            const float* __restrict__ bih_b, const float* __restrict__ bhh_b,
                            float* __restrict__ bias2s,
                            const float* __restrict__ fc_w, unsigned short* __restrict__ fcwF) {
    int blk = blockIdx.x;
    if (blk < 384) {
        int i = blk * 256 + threadIdx.x;
        if (i < 768 * 128) {
            int e3 = i >> 7, c = i & 127;
            wT[i] = conv_w[c * 768 + e3];
        }
    } else if (blk < 2432) {
        // K=32 fp8 B-frag layout: idx bits e:3 | lane:6 | g:2 | kt:3 | w:4 | d:1
        int i = (blk - 384) * 256 + threadIdx.x;
        int e = i & 7;
        int lane = (i >> 3) & 63;
        int g = (i >> 9) & 3;
        int kt = (i >> 11) & 7;
        int w = (i >> 14) & 15;
        int d = (i >> 18) & 1;
        const float* src = d ? whh_b : whh_f;
        int j = w * 16 + (lane & 15);
        int k = kt * 32 + (lane >> 4) * 8 + e;
        float sc = scale[d * 1024 + j * 4 + g];
        whhF8[i] = f2fp8(src[(g * 256 + j) * 256 + k] / sc);
    } else if (blk < 3456) {
        int i = (blk - 2432) * 256 + threadIdx.x;
        int e = i & 7;
        int lane = (i >> 3) & 63;
        int kt = (i >> 9) & 3;
        int ctg = (i >> 11) & 63;
        int d = (i >> 17) & 1;
        const float* src = d ? wih_b : wih_f;
        int row = lane & 15;
        int cell = ctg * 4 + (row >> 2), g = row & 3;
        int k = kt * 32 + (lane >> 4) * 8 + e;
        wihF[i] = f2bf(src[(g * 256 + cell) * 128 + k] * KSC[g]);
    } else if (blk < 3464) {
        int i = (blk - 3456) * 256 + threadIdx.x;
        int d = i >> 10;
        int col = i & 1023;
        const float* bi = d ? bih_b : bih_f;
        const float* bh = d ? bhh_b : bhh_f;
        int g = col & 3, j = col >> 2;
        bias2s[(size_t)d * NG + col] = (bi[g * 256 + j] + bh[g * 256 + j]) * KSC[g];
    } else {
        // fc_w^T bf16 B-frags: idx = (kt*64 + lane)*8 + e; n = lane&15, k = kt*32+(lane>>4)*8+e
        int i = (blk - 3464) * 256 + threadIdx.x;
        if (i < 8192) {
            int e = i & 7;
            int lane = (i >> 3) & 63;
            int kt = (i >> 9) & 15;
            int n = lane & 15;
            int k = kt * 32 + (lane >> 4) * 8 + e;
            fcwF[i] = f2bf(fc_w[n * NH + k]);
        }
    }
}

// ---------------- embedding + conv1d(k=3,pad=1) + relu -> bf16 feat ----------------
__global__ __launch_bounds__(128) void k_conv(const int* __restrict__ x,
                                              const float* __restrict__ table,
                                              const float* __restrict__ wT,
                                              const float* __restrict__ conv_b,
                                              unsigned short* __restrict__ feat) {
    int b = blockIdx.y;
    int s0 = blockIdx.x * 8;
    int c = threadIdx.x;
    __shared__ float win[10][NE];
    for (int i = 0; i < 10; ++i) {
        int s = s0 - 1 + i;
        if (s < 0 || s >= NS) {
            for (int e = c; e < NE; e += 128) win[i][e] = 0.f;
        } else {
            int tok = x[b * NS + s];
            const float* row = table + (size_t)tok * NE;
            for (int e = c; e < NE; e += 128) win[i][e] = row[e];
        }
    }
    __syncthreads();
    float acc[8];
    float bc = conv_b[c];
#pragma unroll
    for (int p = 0; p < 8; ++p) acc[p] = bc;
    for (int e = 0; e < NE; ++e) {
        float r[10];
#pragma unroll
        for (int i = 0; i < 10; ++i) r[i] = win[i][e];
#pragma unroll
        for (int k = 0; k < 3; ++k) {
            float wv = wT[(e * 3 + k) * NC + c];
#pragma unroll
            for (int p = 0; p < 8; ++p) acc[p] += wv * r[p + k];
        }
    }
#pragma unroll
    for (int p = 0; p < 8; ++p) {
        feat[((size_t)b * NS + s0 + p) * NC + c] = f2bf(fmaxf(acc[p], 0.f));
    }
}

// ---------------- input-side gates via bf16 MFMA, 32 pairs/block ----------------
__global__ __launch_bounds__(256) void k_xgate(const unsigned short* __restrict__ feat,
                                               const unsigned short* __restrict__ wihF,
                                               const float* __restrict__ bias2s,
                                               unsigned short* __restrict__ xg) {
    int d = blockIdx.y;
    int p0 = blockIdx.x * 32;
    int tid = threadIdx.x;
    int w = tid >> 6, l = tid & 63;
    int l15 = l & 15, lq = l >> 4;
    int pA = p0 + l15, pB = p0 + 16 + l15;
    int bA = pA & 31, sA = pA >> 5;
    int bB = pB & 31, sB = pB >> 5;
    const unsigned short* fpA = feat + ((size_t)bA * NS + sA) * NC + lq * 8;
    const unsigned short* fpB = feat + ((size_t)bB * NS + sB) * NC + lq * 8;
    bf16x8 bfA[4], bfB[4];
#pragma unroll
    for (int kt = 0; kt < 4; ++kt) {
        bfA[kt] = *(const bf16x8*)(fpA + kt * 32);
        bfB[kt] = *(const bf16x8*)(fpB + kt * 32);
    }
    const unsigned short* WF = wihF + ((size_t)d << 17);
    unsigned short* XGD = xg + (size_t)d * NS * NB * NG;
#pragma unroll
    for (int ct = 0; ct < 16; ++ct) {
        int ctg = w * 16 + ct;
        int cell = ctg * 4 + lq;
        float4 bv = *(const float4*)(bias2s + (size_t)d * NG + cell * 4);
        f32x4 accA = {bv.x, bv.y, bv.z, bv.w};
        f32x4 accB = accA;
#pragma unroll
        for (int kt = 0; kt < 4; ++kt) {
            bf16x8 af = *(const bf16x8*)(WF + (((size_t)ctg * 4 + kt) * 64 + l) * 8);
            accA = __builtin_amdgcn_mfma_f32_16x16x32_bf16(af, bfA[kt], accA, 0, 0, 0);
            accB = __builtin_amdgcn_mfma_f32_16x16x32_bf16(af, bfB[kt], accB, 0, 0, 0);
        }
        unsigned long long hA = (unsigned long long)f2bf(accA[0])
                              | ((unsigned long long)f2bf(accA[1]) << 16)
                              | ((unsigned long long)f2bf(accA[2]) << 32)
                              | ((unsigned long long)f2bf(accA[3]) << 48);
        unsigned long long hB = (unsigned long long)f2bf(accB[0])
                              | ((unsigned long long)f2bf(accB[1]) << 16)
                              | ((unsigned long long)f2bf(accB[2]) << 32)
                              | ((unsigned long long)f2bf(accB[3]) << 48);
        *(unsigned long long*)(XGD + (size_t)pA * 1024 + cell * 4) = hA;
        *(unsigned long long*)(XGD + (size_t)pB * 1024 + cell * 4) = hB;
    }
}

// ---------------- LSTM recurrence: fp8 MFMA K=32, W register-resident (round-14 exact) ------
__global__ __launch_bounds__(1024, 1) void k_lstm2(const unsigned char* __restrict__ whhF8,
                                                   const float* __restrict__ scale,
                                                   const unsigned short* __restrict__ xg,
                                                   unsigned short* __restrict__ hcat) {
    int bid = blockIdx.x;
    int d = bid >> 1, bh = bid & 1;
    int tid = threadIdx.x;
    int w = tid >> 6, l = tid & 63;
    int l15 = l & 15, lq = l >> 4;
    __shared__ unsigned char hbuf[2][16][280];
    for (int i = tid; i < 2 * 16 * 280; i += 1024) (&hbuf[0][0][0])[i] = 0;
    unsigned long long wf[32];
    const unsigned char* wp = whhF8 + ((size_t)(d * 16 + w) << 14) + (size_t)l * 8;
#pragma unroll
    for (int f = 0; f < 32; ++f) wf[f] = *(const unsigned long long*)(wp + f * 512);
    int cell = w * 16 + l15;
    float csc[4];
#pragma unroll
    for (int g = 0; g < 4; ++g)
        csc[g] = scale[d * 1024 + cell * 4 + g] * KSC[g];
    const unsigned short* XG = xg + (size_t)d * NS * NB * NG;
    float cst[4] = {};
    __syncthreads();
    int cur = 0;
    unsigned long long xq[4];
    {
        int s0 = d ? (NS - 1) : 0;
#pragma unroll
        for (int r = 0; r < 4; ++r)
            xq[r] = *(const unsigned long long*)(
                XG + (size_t)(s0 * 32 + bh * 16 + lq * 4 + r) * 1024 + cell * 4);
    }
    for (int step = 0; step < NS; ++step) {
        int s = d ? (NS - 1 - step) : step;
        unsigned long long xn[4];
        {
            int stn = (step + 1 < NS) ? step + 1 : step;
            int sn = d ? (NS - 1 - stn) : stn;
#pragma unroll
            for (int r = 0; r < 4; ++r)
                xn[r] = *(const unsigned long long*)(
                    XG + (size_t)(sn * 32 + bh * 16 + lq * 4 + r) * 1024 + cell * 4);
        }
        f32x4 acc[4];
#pragma unroll
        for (int g = 0; g < 4; ++g) acc[g] = (f32x4){0.f, 0.f, 0.f, 0.f};
#pragma unroll
        for (int kt = 0; kt < 8; ++kt) {
            unsigned long long a = *(const unsigned long long*)&hbuf[cur][l15][kt * 32 + lq * 8];
#pragma unroll
            for (int g = 0; g < 4; ++g)
                acc[g] = __builtin_amdgcn_mfma_f32_16x16x32_fp8_fp8(
                    (long long)a, (long long)wf[kt * 4 + g], acc[g], 0, 0, 0);
        }
        int nxt = cur ^ 1;
#pragma unroll
        for (int r = 0; r < 4; ++r) {
            unsigned long long xv = xq[r];
            float pi = fmaf(acc[0][r], csc[0], bf2f((unsigned short)xv));
            float pf = fmaf(acc[1][r], csc[1], bf2f((unsigned short)(xv >> 16)));
            float pg = fmaf(acc[2][r], csc[2], bf2f((unsigned short)(xv >> 32)));
            float po = fmaf(acc[3][r], csc[3], bf2f((unsigned short)(xv >> 48)));
            float si = vrcp(1.f + vexp2(pi));
            float sf = vrcp(1.f + vexp2(pf));
            float tg = fmaf(-2.f, vrcp(1.f + vexp2(pg)), 1.f);
            float so = vrcp(1.f + vexp2(po));
            float c = fmaf(sf, cst[r], si * tg);
            cst[r] = c;
            float tc = fmaf(-2.f, vrcp(1.f + vexp2(2.885390082f * c)), 1.f);
            float h = so * tc;
            int b = lq * 4 + r;
            __builtin_nontemporal_store(f2bf(h),
                hcat + (size_t)(s * 32 + bh * 16 + b) * NH + d * NHD + cell);
            hbuf[nxt][b][cell] = f2fp8(h);
        }
        __syncthreads();
        cur = nxt;
#pragma unroll
        for (int r = 0; r < 4; ++r) xq[r] = xn[r];
    }
}

// ---------------- FC to emissions via bf16 MFMA: em[p][t], M=pairs N=16 K=512 ----------------
__global__ __launch_bounds__(256) void k_fc(const unsigned short* __restrict__ hcat,
                                            const unsigned short* __restrict__ fcwF,
                                            const float* __restrict__ fc_b,
                                            float* __restrict__ em) {
    int tid = threadIdx.x;
    int w = tid >> 6, l = tid & 63;
    int l15 = l & 15, lq = l >> 4;
    int p0 = blockIdx.x * 64 + w * 16;
    bf16x8 bfr[16];
#pragma unroll
    for (int kt = 0; kt < 16; ++kt)
        bfr[kt] = *(const bf16x8*)(fcwF + ((size_t)kt * 64 + l) * 8);
    const unsigned short* hp = hcat + (size_t)(p0 + l15) * NH + lq * 8;
    f32x4 acc = {0.f, 0.f, 0.f, 0.f};
#pragma unroll
    for (int kt = 0; kt < 16; ++kt) {
        bf16x8 af = *(const bf16x8*)(hp + kt * 32);
        acc = __builtin_amdgcn_mfma_f32_16x16x32_bf16(af, bfr[kt], acc, 0, 0, 0);
    }
    float bias = fc_b[l15];
#pragma unroll
    for (int r = 0; r < 4; ++r)
        em[(size_t)(p0 + lq * 4 + r) * NT + l15] = acc[r] + bias;
}

// ---------------- CRF NLL per batch: wave-parallel forward algorithm ----------------
__global__ __launch_bounds__(64) void k_crf(const float* __restrict__ em,
                                            const int* __restrict__ tags,
                                            const int* __restrict__ mask,
                                            const float* __restrict__ start_t,
                                            const float* __restrict__ end_t,
                                            const float* __restrict__ trans,
                                            float* __restrict__ res) {
    int b = blockIdx.x;
    int tid = threadIdx.x;
    __shared__ float em_sh[NS * NT];
    __shared__ float tr[NT * NT];
    __shared__ float alpha_sh[NT];
    __shared__ float msk[NS];
    __shared__ float sc_sh;
    for (int i = tid; i < NT * NT; i += 64) tr[i] = trans[i];
    for (int i = tid; i < NS * NT; i += 64) {
        int s = i >> 4, t = i & 15;
        em_sh[i] = em[((size_t)s * NB + b) * NT + t];
    }
    for (int s = tid; s < NS; s += 64) msk[s] = (float)mask[b * NS + s];
    __syncthreads();
    float part = 0.f, msum = 0.f;
    for (int s = tid; s < NS; s += 64) msum += msk[s];
    for (int s = 1 + tid; s < NS; s += 64) {
        int pv = tags[b * NS + s - 1], cu = tags[b * NS + s];
        part += (tr[pv * NT + cu] + em_sh[s * NT + cu]) * msk[s];
    }
#pragma unroll
    for (int o = 32; o > 0; o >>= 1) {
        part += __shfl_down(part, o);
        msum += __shfl_down(msum, o);
    }
    if (tid == 0) {
        int t0 = tags[b * NS];
        int send = (int)msum - 1;
        sc_sh = start_t[t0] + em_sh[t0] + part + end_t[tags[b * NS + send]];
    }
    if (tid < NT) alpha_sh[tid] = start_t[tid] + em_sh[tid];
    __syncthreads();
    int t_to = tid >> 2, q = tid & 3;
    for (int s = 1; s < NS; ++s) {
        float v0 = alpha_sh[q * 4 + 0] + tr[(q * 4 + 0) * NT + t_to];
        float v1 = alpha_sh[q * 4 + 1] + tr[(q * 4 + 1) * NT + t_to];
        float v2 = alpha_sh[q * 4 + 2] + tr[(q * 4 + 2) * NT + t_to];
        float v3 = alpha_sh[q * 4 + 3] + tr[(q * 4 + 3) * NT + t_to];
        float mx = fmaxf(fmaxf(v0, v1), fmaxf(v2, v3));
        mx = fmaxf(mx, __shfl_xor(mx, 1));
        mx = fmaxf(mx, __shfl_xor(mx, 2));
        float nmx = -1.442695041f * mx;
        float ss = vexp2(fmaf(v0, 1.442695041f, nmx)) + vexp2(fmaf(v1, 1.442695041f, nmx))
                 + vexp2(fmaf(v2, 1.442695041f, nmx)) + vexp2(fmaf(v3, 1.442695041f, nmx));
        ss += __shfl_xor(ss, 1);
        ss += __shfl_xor(ss, 2);
        float nv = mx + 0.6931471806f * vlog2(ss) + em_sh[s * NT + t_to];
        float old = alpha_sh[t_to];
        nv = (msk[s] > 0.f) ? nv : old;
        __syncthreads();
        if (q == 0) alpha_sh[t_to] = nv;
        __syncthreads();
    }
    if (tid == 0) {
        float mx = -1e30f;
        for (int t = 0; t < NT; ++t) mx = fmaxf(mx, alpha_sh[t] + end_t[t]);
        float sum = 0.f;
        for (int t = 0; t < NT; ++t) sum += vexp2(1.442695041f * (alpha_sh[t] + end_t[t] - mx));
        res[b] = sc_sh - (mx + 0.6931471806f * vlog2(sum));
    }
}

__global__ void k_final(const float* __restrict__ res, float* __restrict__ out) {
    int tid = threadIdx.x;
    float v = (tid < NB) ? res[tid] : 0.f;
#pragma unroll
    for (int o = 32; o > 0; o >>= 1) v += __shfl_down(v, o);
    if (tid == 0) out[0] = -v / NB;
}

// ---------------- workspace layout ----------------
constexpr size_t SZ_FEAT  = (size_t)NB * NS * NC * 2;       // 4 MB (bf16)
constexpr size_t SZ_WT    = (size_t)768 * 128 * 4;          // 384 KB
constexpr size_t SZ_WHHF8 = (size_t)(1 << 19);              // 512 KB (fp8 frags)
constexpr size_t SZ_SCALE = (size_t)2 * 1024 * 4;           // 8 KB
constexpr size_t SZ_WIHF  = (size_t)(1 << 18) * 2;          // 512 KB (bf16 A-frags)
constexpr size_t SZ_BIAS  = (size_t)2 * NG * 4;             // 8 KB
constexpr size_t SZ_FCWF  = (size_t)8192 * 2;               // 16 KB (bf16 B-frags)
constexpr size_t SZ_XG    = (size_t)2 * NS * NB * NG * 2;   // 64 MB (bf16)
constexpr size_t SZ_HCAT  = (size_t)NS * NB * NH * 2;       // 16 MB (bf16)
constexpr size_t SZ_EM    = (size_t)NS * NB * NT * 4;       // 1 MB

constexpr size_t OFF_FEAT  = 0;
constexpr size_t OFF_WT    = OFF_FEAT + SZ_FEAT;
constexpr size_t OFF_WHHF8 = OFF_WT + SZ_WT;
constexpr size_t OFF_SCALE = OFF_WHHF8 + SZ_WHHF8;
constexpr size_t OFF_WIHF  = OFF_SCALE + SZ_SCALE;
constexpr size_t OFF_BIAS  = OFF_WIHF + SZ_WIHF;
constexpr size_t OFF_FCWF  = OFF_BIAS + SZ_BIAS;
constexpr size_t OFF_XG    = OFF_FCWF + SZ_FCWF;
constexpr size_t OFF_HCAT  = OFF_XG + SZ_XG;
constexpr size_t OFF_EM    = OFF_HCAT + SZ_HCAT;
constexpr size_t OFF_RES   = OFF_EM + SZ_EM;

extern "C" void kernel_launch(void* const* d_in, const int* in_sizes, int n_in,
                              void* d_out, int out_size, void* d_ws, size_t ws_size,
                              hipStream_t stream) {
    const int* x        = (const int*)d_in[0];
    const int* mask     = (const int*)d_in[1];
    const int* tags     = (const int*)d_in[2];
    const float* table  = (const float*)d_in[3];
    const float* conv_w = (const float*)d_in[4];
    const float* conv_b = (const float*)d_in[5];
    const float* wih_f  = (const float*)d_in[6];
    const float* whh_f  = (const float*)d_in[7];
    const float* bih_f  = (const float*)d_in[8];
    const float* bhh_f  = (const float*)d_in[9];
    const float* wih_b  = (const float*)d_in[10];
    const float* whh_b  = (const float*)d_in[11];
    const float* bih_b  = (const float*)d_in[12];
    const float* bhh_b  = (const float*)d_in[13];
    const float* fc_w   = (const float*)d_in[14];
    const float* fc_b   = (const float*)d_in[15];
    const float* start_t = (const float*)d_in[16];
    const float* end_t  = (const float*)d_in[17];
    const float* trans  = (const float*)d_in[18];

    char* ws = (char*)d_ws;
    unsigned short* feat = (unsigned short*)(ws + OFF_FEAT);
    float* wT   = (float*)(ws + OFF_WT);
    unsigned char* whhF8 = (unsigned char*)(ws + OFF_WHHF8);
    float* scale = (float*)(ws + OFF_SCALE);
    unsigned short* wihF = (unsigned short*)(ws + OFF_WIHF);
    float* bias2s = (float*)(ws + OFF_BIAS);
    unsigned short* fcwF = (unsigned short*)(ws + OFF_FCWF);
    unsigned short* xg = (unsigned short*)(ws + OFF_XG);
    unsigned short* hcat = (unsigned short*)(ws + OFF_HCAT);
    float* em   = (float*)(ws + OFF_EM);
    float* res  = (float*)(ws + OFF_RES);

    k_prep_scale<<<dim3(256, 2), 256, 0, stream>>>(whh_f, whh_b, scale);
    k_prep_main<<<dim3(3496), 256, 0, stream>>>(conv_w, wT, whh_f, whh_b, scale, whhF8,
                                                wih_f, wih_b, wihF,
                                                bih_f, bhh_f, bih_b, bhh_b, bias2s,
                                                fc_w, fcwF);
    k_conv<<<dim3(NS / 8, NB), 128, 0, stream>>>(x, table, wT, conv_b, feat);
    k_xgate<<<dim3(NS * NB / 32, 2), 256, 0, stream>>>(feat, wihF, bias2s, xg);
    k_lstm2<<<dim3(4), 1024, 0, stream>>>(whhF8, scale, xg, hcat);
    k_fc<<<dim3(NS * NB / 64), 256, 0, stream>>>(hcat, fcwF, fc_b, em);
    k_crf<<<dim3(NB), 64, 0, stream>>>(em, tags, mask, start_t, end_t, trans, res);
    k_final<<<dim3(1), 64, 0, stream>>>(res, (float*)d_out);
}